// Round 14
// baseline (137.548 us; speedup 1.0000x reference)
//
#include <hip/hip_runtime.h>
#include <hip/hip_bf16.h>

// Grouped GEMM: out[e,s,o] = sum_i x[e,s,i] * w[e,o,i]
// E=8, S=8192 tok/expert, O=512, I=1024, fp32 in/out, bf16 MFMA compute.
// R14: TLP fix. R13's loop verbatim, but wave tile 64x64 (acc 64 regs,
//      total ~158 -> 3 waves/SIMD) in 4-wave blocks (64x256 tile),
//      grid 2048 = 8e x 128m x 2n -> ~3 independent blocks per CU.
//      Barriers sync only 4 waves; 12 waves/CU hide each other's
//      ds_read/vmcnt/cvt stalls (m114). B fabric doubles (BN 256) but
//      stays under the 63us HBM-compulsory pool.

#define NE 8
#define NO 512
#define NI 1024
#define NS 8192

#define BM 64
#define BN 256
#define BK 64
#define NP (NI / BK)   // 16 periods

typedef __attribute__((ext_vector_type(4))) float f32x4;
typedef __attribute__((ext_vector_type(4))) short s16x4;
typedef __attribute__((ext_vector_type(8))) short s16x8;

__device__ __forceinline__ s16x4 cvt4(f32x4 a) {
    s16x4 r;
    r[0] = (short)__builtin_bit_cast(unsigned short, __float2bfloat16(a[0]));
    r[1] = (short)__builtin_bit_cast(unsigned short, __float2bfloat16(a[1]));
    r[2] = (short)__builtin_bit_cast(unsigned short, __float2bfloat16(a[2]));
    r[3] = (short)__builtin_bit_cast(unsigned short, __float2bfloat16(a[3]));
    return r;
}

// ---- pass 0: W fp32 -> bf16, MFMA B-fragment lane order (R3-verified) ----
// Wpk(e, g, kt32, l, j) = bf16(W[e][g*16 + (l&15)][kt32*32 + (l>>4)*8 + j])
__global__ __launch_bounds__(256)
void pack_w(const float* __restrict__ W, short* __restrict__ Wpk) {
    int idx  = blockIdx.x * 256 + threadIdx.x;  // 0 .. 524287
    int l    = idx & 63;
    int kt32 = (idx >> 6) & 31;
    int g    = (idx >> 11) & 31;
    int e    = idx >> 16;
    const float* src = W + (size_t)(e * NO + g * 16 + (l & 15)) * NI
                         + kt32 * 32 + (l >> 4) * 8;
    f32x4 a = *(const f32x4*)src;
    f32x4 b = *(const f32x4*)(src + 4);
    s16x4 lo = cvt4(a), hi = cvt4(b);
    s16x8 r;
    r[0] = lo[0]; r[1] = lo[1]; r[2] = lo[2]; r[3] = lo[3];
    r[4] = hi[0]; r[5] = hi[1]; r[6] = hi[2]; r[7] = hi[3];
    *(s16x8*)(Wpk + (size_t)idx * 8) = r;
}

// ---- main grouped GEMM ----
__global__ __launch_bounds__(256, 3)
void moe_gemm(const float* __restrict__ X,
              const short* __restrict__ Wpk,
              float* __restrict__ Out) {
    // 2048 blocks = 8 experts x 128 mblk x 2 nblk. e = bid&7 -> expert/XCD.
    int bid  = blockIdx.x;
    int e    = bid & 7;
    int nblk = (bid >> 3) & 1;
    int mblk = bid >> 4;

    const float* Ap = X   + ((size_t)e * NS + (size_t)mblk * BM) * NI;
    const short* Bp = Wpk + (size_t)e * (32 * 32 * 64 * 8);
    float*       Cp = Out + ((size_t)e * NS + (size_t)mblk * BM) * NO + nblk * BN;

    __shared__ short lA[2][BM * BK];   // 2 x 8 KiB

    const int tid  = threadIdx.x;
    const int lane = tid & 63;
    const int wn   = tid >> 6;    // 0..3 -> cols [wn*64, +64) within BN=256
    const int l15  = lane & 15;
    const int lhi  = lane >> 4;   // 0..3
    const int gbase = nblk * 16 + wn * 4;   // global 16-col fragment group

    f32x4 acc[4][4];
#pragma unroll
    for (int i = 0; i < 4; ++i)
#pragma unroll
        for (int j = 0; j < 4; ++j)
            acc[i][j] = (f32x4){0.f, 0.f, 0.f, 0.f};

    f32x4 ar[4];                 // A staging: 4 x f32x4 / thread (64x64 fp32)
    s16x8 bfA[4], bfB[4], af[4]; // named B double-buffer (rule #20)

    // A: unit u = tid + i*256 over 1024 f32x4-chunks of the 64x64 tile.
    // row = u>>4 (0..63), c4 = u&15. 16 lanes x 16 B = 256 B/row, coalesced.
#define AISSUE(p)                                                              \
    do {                                                                       \
        _Pragma("unroll") for (int i = 0; i < 4; ++i) {                        \
            int u = tid + i * 256;                                             \
            ar[i] = *(const f32x4*)(Ap + (size_t)(u >> 4) * NI +               \
                                    (p) * BK + (u & 15) * 4);                  \
        }                                                                      \
    } while (0)

    // A write: 16B-chunk c16 = c4>>1, phys = c16 ^ (row&7). (R8-verified)
#define AWRITE(buf)                                                            \
    do {                                                                       \
        _Pragma("unroll") for (int i = 0; i < 4; ++i) {                        \
            int u    = tid + i * 256;                                          \
            int row  = u >> 4;                                                 \
            int c4   = u & 15;                                                 \
            int phys = (c4 >> 1) ^ (row & 7);                                  \
            *(s16x4*)&lA[buf][row * BK + phys * 8 + (c4 & 1) * 4] = cvt4(ar[i]); \
        }                                                                      \
    } while (0)

    // B frag (gbase+ni, kt32): 16 B/lane, lanes contiguous (L2-resident Wpk).
#define BLOAD(kt, dst)                                                         \
    do {                                                                       \
        _Pragma("unroll") for (int ni = 0; ni < 4; ++ni)                       \
            dst[ni] = *(const s16x8*)(Bp +                                     \
                ((size_t)((gbase + ni) * 32 + (kt)) * 64 + lane) * 8);         \
    } while (0)

    // A frags, k-half kk: row r = mi*16+l15, phys = (kk*4+lhi) ^ (r&7).
#define READA(c, kk)                                                           \
    do {                                                                       \
        _Pragma("unroll") for (int mi = 0; mi < 4; ++mi) {                     \
            int r  = mi * 16 + l15;                                            \
            af[mi] = *(const s16x8*)&lA[c][r * BK +                            \
                                           ((((kk) * 4 + lhi) ^ (r & 7)) << 3)]; \
        }                                                                      \
    } while (0)

#define MFMA(bf)                                                               \
    do {                                                                       \
        __builtin_amdgcn_s_setprio(1);                                         \
        _Pragma("unroll") for (int mi = 0; mi < 4; ++mi)                       \
            _Pragma("unroll") for (int ni = 0; ni < 4; ++ni)                   \
                acc[mi][ni] = __builtin_amdgcn_mfma_f32_16x16x32_bf16(         \
                    af[mi], bf[ni], acc[mi][ni], 0, 0, 0);                     \
        __builtin_amdgcn_s_setprio(0);                                         \
    } while (0)

#define BAR()   __builtin_amdgcn_s_barrier()
#define LGKM0() asm volatile("s_waitcnt lgkmcnt(0)" ::: "memory")
#define VM(n)   asm volatile("s_waitcnt vmcnt(" #n ")" ::: "memory")

    // ---- Prologue. Invariant entering period j:
    //      lA[j&1] = A(j); bfA,bfB = B(2j),B(2j+1) in vm queue;
    //      queue = [B8(j) oldest, A4(j+1)]. ----
    AISSUE(0);
    VM(0);
    AWRITE(0);
    BLOAD(0, bfA);     // B8(0)...
    BLOAD(1, bfB);
    AISSUE(1);         // A4(1)
    LGKM0();
    BAR();

#pragma unroll 1
    for (int j = 0; j < NP - 1; ++j) {
        const int c = j & 1;
        // consume-first: everything below VM(4) is resident.
        VM(4);                       // drain B8(j); keep A4(j+1)
        READA(c, 0);
        MFMA(bfA);
        BLOAD(2 * j + 2, bfA);       // B for period j+1, first half
        READA(c, 1);
        MFMA(bfB);
        BLOAD(2 * j + 3, bfB);       // B for period j+1, second half
        // stage-behind:
        VM(8);                       // drain A4(j+1); keep B8(j+1)
        AWRITE(c ^ 1);
        if (j < NP - 2) AISSUE(j + 2);
        LGKM0();                     // own ds_writes visible
        BAR();
    }
    // ---- Period 15: consume only. Queue entering: [B8(15)]. ----
    VM(4);
    READA(1, 0);
    MFMA(bfA);
    VM(0);
    READA(1, 1);
    MFMA(bfB);

    // Epilogue: D frag (mi,ni): m = lhi*4 + rr, n = l15 (verified layout).
#pragma unroll
    for (int mi = 0; mi < 4; ++mi) {
#pragma unroll
        for (int rr = 0; rr < 4; ++rr) {
            int row   = mi * 16 + lhi * 4 + rr;
            float* cp = Cp + (size_t)row * NO + wn * 64 + l15;
#pragma unroll
            for (int ni = 0; ni < 4; ++ni)
                cp[ni * 16] = acc[mi][ni][rr];
        }
    }
#undef AISSUE
#undef AWRITE
#undef BLOAD
#undef READA
#undef MFMA
#undef BAR
#undef LGKM0
#undef VM
}

extern "C" void kernel_launch(void* const* d_in, const int* in_sizes, int n_in,
                              void* d_out, int out_size, void* d_ws, size_t ws_size,
                              hipStream_t stream) {
    const float* X = (const float*)d_in[0];
    const float* W = (const float*)d_in[1];
    float* Out     = (float*)d_out;
    short* Wpk     = (short*)d_ws;   // 8 MiB

    hipLaunchKernelGGL(pack_w, dim3(2048), dim3(256), 0, stream, W, Wpk);
    hipLaunchKernelGGL(moe_gemm, dim3(NE * (NS / BM) * (NO / BN)), dim3(256), 0,
                       stream, X, Wpk, Out);
}

// Round 15
// 118.357 us; speedup vs baseline: 1.1621x; 1.1621x over previous
//
#include <hip/hip_runtime.h>
#include <hip/hip_bf16.h>

// Grouped GEMM: out[e,s,o] = sum_i x[e,s,i] * w[e,o,i]
// E=8, S=8192 tok/expert, O=512, I=1024, fp32 in/out, bf16 MFMA compute.
// R15: R13 frame (BM=128 x BN=512, 8 waves, consume-first BK=64 periods,
//      reg-B from packed Wpk, expert-per-XCD) with MFMA shape switched to
//      32x32x16 (half the instructions, 2382 vs 2075 TF ceiling).
//      Wave tile 128x64 = 4m x 2n tiles of 32x32; acc = 8 x f32x16.
//      B packed per 32x32 lane order: frag(e,g,kt16): lane l holds
//      W[e][g*32+(l&31)][kt16*16+(l>>5)*8+j].  A-LDS swizzle unchanged;
//      read chunk c16 = ks*2+(l>>5), phys = c16^(row&7).

#define NE 8
#define NO 512
#define NI 1024
#define NS 8192

#define BM 128
#define BK 64
#define NP (NI / BK)   // 16 periods

typedef __attribute__((ext_vector_type(4))) float f32x4;
typedef __attribute__((ext_vector_type(16))) float f32x16;
typedef __attribute__((ext_vector_type(4))) short s16x4;
typedef __attribute__((ext_vector_type(8))) short s16x8;

__device__ __forceinline__ s16x4 cvt4(f32x4 a) {
    s16x4 r;
    r[0] = (short)__builtin_bit_cast(unsigned short, __float2bfloat16(a[0]));
    r[1] = (short)__builtin_bit_cast(unsigned short, __float2bfloat16(a[1]));
    r[2] = (short)__builtin_bit_cast(unsigned short, __float2bfloat16(a[2]));
    r[3] = (short)__builtin_bit_cast(unsigned short, __float2bfloat16(a[3]));
    return r;
}

// ---- pass 0: W fp32 -> bf16, 32x32x16 B-fragment lane order ----
// Wpk frag id f = (e*16 + g)*64 + kt16; element (lane l, j):
//   W[e][g*32 + (l&31)][kt16*16 + (l>>5)*8 + j]
__global__ __launch_bounds__(256)
void pack_w(const float* __restrict__ W, short* __restrict__ Wpk) {
    int idx  = blockIdx.x * 256 + threadIdx.x;  // 0 .. 524287
    int l    = idx & 63;
    int kt16 = (idx >> 6) & 63;
    int g    = (idx >> 12) & 15;
    int e    = idx >> 16;
    const float* src = W + (size_t)(e * NO + g * 32 + (l & 31)) * NI
                         + kt16 * 16 + (l >> 5) * 8;
    f32x4 a = *(const f32x4*)src;
    f32x4 b = *(const f32x4*)(src + 4);
    s16x4 lo = cvt4(a), hi = cvt4(b);
    s16x8 r;
    r[0] = lo[0]; r[1] = lo[1]; r[2] = lo[2]; r[3] = lo[3];
    r[4] = hi[0]; r[5] = hi[1]; r[6] = hi[2]; r[7] = hi[3];
    *(s16x8*)(Wpk + (size_t)idx * 8) = r;
}

// ---- main grouped GEMM ----
__global__ __launch_bounds__(512, 1)
void moe_gemm(const float* __restrict__ X,
              const short* __restrict__ Wpk,
              float* __restrict__ Out) {
    // 512 blocks = 8 experts x 64 mblk. e = bid&7 -> one expert per XCD.
    int bid  = blockIdx.x;
    int e    = bid & 7;
    int mblk = bid >> 3;

    const float* Ap = X   + ((size_t)e * NS + (size_t)mblk * BM) * NI;
    const short* Bp = Wpk + (size_t)e * (16 * 64 * 64 * 8);
    float*       Cp = Out + ((size_t)e * NS + (size_t)mblk * BM) * NO;

    __shared__ short lA[2][BM * BK];   // 2 x 16 KiB

    const int tid  = threadIdx.x;
    const int lane = tid & 63;
    const int wn   = tid >> 6;    // 0..7 -> cols [wn*64, +64)
    const int l31  = lane & 31;
    const int lh   = lane >> 5;   // 0..1

    f32x16 acc[4][2];
#pragma unroll
    for (int i = 0; i < 4; ++i)
#pragma unroll
        for (int j = 0; j < 2; ++j)
            acc[i][j] = (f32x16){0.f};

    f32x4 ar[4];                 // A staging: 4 x f32x4 / thread (128x64 fp32)
    s16x8 bfA[4], bfB[4], af[4]; // bfX[ni*2+s]: ni col-tile, s k-substep

    // A: unit u = tid + i*512 over 2048 f32x4-chunks of the 128x64 tile.
#define AISSUE(p)                                                              \
    do {                                                                       \
        _Pragma("unroll") for (int i = 0; i < 4; ++i) {                        \
            int u = tid + i * 512;                                             \
            ar[i] = *(const f32x4*)(Ap + (size_t)(u >> 4) * NI +               \
                                    (p) * BK + (u & 15) * 4);                  \
        }                                                                      \
    } while (0)

    // A write: 16B-chunk c16 = c4>>1, phys = c16 ^ (row&7). (R8-verified)
#define AWRITE(buf)                                                            \
    do {                                                                       \
        _Pragma("unroll") for (int i = 0; i < 4; ++i) {                        \
            int u    = tid + i * 512;                                          \
            int row  = u >> 4;                                                 \
            int c4   = u & 15;                                                 \
            int phys = (c4 >> 1) ^ (row & 7);                                  \
            *(s16x4*)&lA[buf][row * BK + phys * 8 + (c4 & 1) * 4] = cvt4(ar[i]); \
        }                                                                      \
    } while (0)

    // B frags for period j, half h (k substeps s=0,1): g = wn*2+ni,
    // kt16 = j*4 + h*2 + s. 4 x 16B/lane, lanes contiguous (L2-resident).
#define BLOADH(j, h, dst)                                                      \
    do {                                                                       \
        _Pragma("unroll") for (int ni = 0; ni < 2; ++ni)                       \
            _Pragma("unroll") for (int s = 0; s < 2; ++s)                      \
                dst[ni * 2 + s] = *(const s16x8*)(Bp +                         \
                    ((size_t)((wn * 2 + ni) * 64 + ((j) * 4 + (h) * 2 + s))    \
                     * 64 + lane) * 8);                                        \
    } while (0)

    // A frags, k-substep ks (K=16): row r = mi*32+l31,
    // c16 = ks*2+lh, phys = c16 ^ (r&7).
#define READA(c, ks)                                                           \
    do {                                                                       \
        _Pragma("unroll") for (int mi = 0; mi < 4; ++mi) {                     \
            int r  = mi * 32 + l31;                                            \
            af[mi] = *(const s16x8*)&lA[c][r * BK +                            \
                                           ((((ks) * 2 + lh) ^ (r & 7)) << 3)]; \
        }                                                                      \
    } while (0)

    // 8 MFMA: 4 mi x 2 ni at one k-substep.
#define MFMA8(b0, b1)                                                          \
    do {                                                                       \
        __builtin_amdgcn_s_setprio(1);                                         \
        _Pragma("unroll") for (int mi = 0; mi < 4; ++mi) {                     \
            acc[mi][0] = __builtin_amdgcn_mfma_f32_32x32x16_bf16(              \
                af[mi], b0, acc[mi][0], 0, 0, 0);                              \
            acc[mi][1] = __builtin_amdgcn_mfma_f32_32x32x16_bf16(              \
                af[mi], b1, acc[mi][1], 0, 0, 0);                              \
        }                                                                      \
        __builtin_amdgcn_s_setprio(0);                                         \
    } while (0)

#define BAR()   __builtin_amdgcn_s_barrier()
#define LGKM0() asm volatile("s_waitcnt lgkmcnt(0)" ::: "memory")
#define VM(n)   asm volatile("s_waitcnt vmcnt(" #n ")" ::: "memory")

    // ---- Prologue. Invariant entering period j:
    //      lA[j&1] = A(j); vm queue = [B8(j) oldest, A4(j+1)]. ----
    AISSUE(0);
    VM(0);
    AWRITE(0);
    BLOADH(0, 0, bfA);   // B8(0)...
    BLOADH(0, 1, bfB);
    AISSUE(1);           // A4(1)
    LGKM0();
    BAR();

#pragma unroll 1
    for (int j = 0; j < NP - 1; ++j) {
        const int c = j & 1;
        // consume-first: everything below VM(4) is resident.
        VM(4);                         // drain B8(j); keep A4(j+1)
        READA(c, 0); MFMA8(bfA[0], bfA[2]);
        READA(c, 1); MFMA8(bfA[1], bfA[3]);
        BLOADH(j + 1, 0, bfA);         // refill just-consumed half
        READA(c, 2); MFMA8(bfB[0], bfB[2]);
        READA(c, 3); MFMA8(bfB[1], bfB[3]);
        BLOADH(j + 1, 1, bfB);
        // stage-behind:
        VM(8);                         // drain A4(j+1); keep B8(j+1)
        AWRITE(c ^ 1);
        if (j < NP - 2) AISSUE(j + 2);
        LGKM0();                       // own ds_writes visible
        BAR();
    }
    // ---- Period 15: consume only. Queue entering: [B8(15)]. ----
    VM(4);                             // bfA half resident
    READA(1, 0); MFMA8(bfA[0], bfA[2]);
    READA(1, 1); MFMA8(bfA[1], bfA[3]);
    VM(0);
    READA(1, 2); MFMA8(bfB[0], bfB[2]);
    READA(1, 3); MFMA8(bfB[1], bfB[3]);

    // Epilogue: 32x32 C/D layout (m74/m101-verified):
    // col = lane&31, row = (reg&3) + 8*(reg>>2) + 4*(lane>>5).
#pragma unroll
    for (int mi = 0; mi < 4; ++mi) {
#pragma unroll
        for (int ni = 0; ni < 2; ++ni) {
#pragma unroll
            for (int q = 0; q < 4; ++q) {
#pragma unroll
                for (int rr = 0; rr < 4; ++rr) {
                    int row = mi * 32 + q * 8 + lh * 4 + rr;
                    Cp[(size_t)row * NO + wn * 64 + ni * 32 + l31] =
                        acc[mi][ni][q * 4 + rr];
                }
            }
        }
    }
#undef AISSUE
#undef AWRITE
#undef BLOADH
#undef READA
#undef MFMA8
#undef BAR
#undef LGKM0
#undef VM
}

extern "C" void kernel_launch(void* const* d_in, const int* in_sizes, int n_in,
                              void* d_out, int out_size, void* d_ws, size_t ws_size,
                              hipStream_t stream) {
    const float* X = (const float*)d_in[0];
    const float* W = (const float*)d_in[1];
    float* Out     = (float*)d_out;
    short* Wpk     = (short*)d_ws;   // 8 MiB

    hipLaunchKernelGGL(pack_w, dim3(2048), dim3(256), 0, stream, W, Wpk);
    hipLaunchKernelGGL(moe_gemm, dim3(NE * (NS / BM)), dim3(512), 0,
                       stream, X, Wpk, Out);
}

// Round 16
// 115.408 us; speedup vs baseline: 1.1918x; 1.0255x over previous
//
#include <hip/hip_runtime.h>
#include <hip/hip_bf16.h>

// Grouped GEMM: out[e,s,o] = sum_i x[e,s,i] * w[e,o,i]
// E=8, S=8192 tok/expert, O=512, I=1024, fp32 in/out, bf16 MFMA compute.
// R16: R13 frame (BM=128 x BN=512, 8 waves, reg-B from packed Wpk,
//      expert-per-XCD, consume-first) with BK 64 -> 128: one BAR+LGKM per
//      128 MFMA (was two). A staged in two 64-col halves reusing ar[4]
//      (reg footprint identical to R13 -- the 252-reg/wave cliff).
//      B refilled intra-period into bfA/bfB (>=1 kk-step lead, L2-safe).
//      Uniform VM(8) maintains queue invariant [B4,B4,A4]; never 0 mid-loop.

#define NE 8
#define NO 512
#define NI 1024
#define NS 8192

#define BM 128
#define BK 128
#define NP (NI / BK)   // 8 periods; kt32 = j*4 + kk (kk = 0..3)

typedef __attribute__((ext_vector_type(4))) float f32x4;
typedef __attribute__((ext_vector_type(4))) short s16x4;
typedef __attribute__((ext_vector_type(8))) short s16x8;

__device__ __forceinline__ s16x4 cvt4(f32x4 a) {
    s16x4 r;
    r[0] = (short)__builtin_bit_cast(unsigned short, __float2bfloat16(a[0]));
    r[1] = (short)__builtin_bit_cast(unsigned short, __float2bfloat16(a[1]));
    r[2] = (short)__builtin_bit_cast(unsigned short, __float2bfloat16(a[2]));
    r[3] = (short)__builtin_bit_cast(unsigned short, __float2bfloat16(a[3]));
    return r;
}

// ---- pass 0: W fp32 -> bf16, MFMA B-fragment lane order (R3-verified) ----
// Wpk(e, g, kt32, l, j) = bf16(W[e][g*16 + (l&15)][kt32*32 + (l>>4)*8 + j])
__global__ __launch_bounds__(256)
void pack_w(const float* __restrict__ W, short* __restrict__ Wpk) {
    int idx  = blockIdx.x * 256 + threadIdx.x;  // 0 .. 524287
    int l    = idx & 63;
    int kt32 = (idx >> 6) & 31;
    int g    = (idx >> 11) & 31;
    int e    = idx >> 16;
    const float* src = W + (size_t)(e * NO + g * 16 + (l & 15)) * NI
                         + kt32 * 32 + (l >> 4) * 8;
    f32x4 a = *(const f32x4*)src;
    f32x4 b = *(const f32x4*)(src + 4);
    s16x4 lo = cvt4(a), hi = cvt4(b);
    s16x8 r;
    r[0] = lo[0]; r[1] = lo[1]; r[2] = lo[2]; r[3] = lo[3];
    r[4] = hi[0]; r[5] = hi[1]; r[6] = hi[2]; r[7] = hi[3];
    *(s16x8*)(Wpk + (size_t)idx * 8) = r;
}

// ---- main grouped GEMM ----
__global__ __launch_bounds__(512, 1)
void moe_gemm(const float* __restrict__ X,
              const short* __restrict__ Wpk,
              float* __restrict__ Out) {
    // 512 blocks = 8 experts x 64 mblk. e = bid&7 -> one expert per XCD.
    int bid  = blockIdx.x;
    int e    = bid & 7;
    int mblk = bid >> 3;

    const float* Ap = X   + ((size_t)e * NS + (size_t)mblk * BM) * NI;
    const short* Bp = Wpk + (size_t)e * (32 * 32 * 64 * 8);
    float*       Cp = Out + ((size_t)e * NS + (size_t)mblk * BM) * NO;

    __shared__ short lA[2][BM * BK];   // 2 x 32 KiB

    const int tid  = threadIdx.x;
    const int lane = tid & 63;
    const int wn   = tid >> 6;    // 0..7 -> cols [wn*64, +64)
    const int l15  = lane & 15;
    const int lhi  = lane >> 4;   // 0..3

    f32x4 acc[8][4];
#pragma unroll
    for (int i = 0; i < 8; ++i)
#pragma unroll
        for (int j = 0; j < 4; ++j)
            acc[i][j] = (f32x4){0.f, 0.f, 0.f, 0.f};

    f32x4 ar[4];                 // A staging: one 128x64 half-tile per fill
    s16x8 bfA[4], bfB[4], af[8]; // named B double-buffer (rule #20)

    // A half-tile h of period p: cols [p*128 + h*64, +64).
    // unit u = tid + i*512 over 2048 f32x4-chunks: row = u>>4, c4 = u&15.
#define AISSUE(p, h)                                                           \
    do {                                                                       \
        _Pragma("unroll") for (int i = 0; i < 4; ++i) {                        \
            int u = tid + i * 512;                                             \
            ar[i] = *(const f32x4*)(Ap + (size_t)(u >> 4) * NI +               \
                                    (p) * BK + (h) * 64 + (u & 15) * 4);       \
        }                                                                      \
    } while (0)

    // A write into half h: 16B-chunk c16 = c4>>1 (0..7), phys = c16^(row&7).
#define AWRITE(buf, h)                                                         \
    do {                                                                       \
        _Pragma("unroll") for (int i = 0; i < 4; ++i) {                        \
            int u    = tid + i * 512;                                          \
            int row  = u >> 4;                                                 \
            int c4   = u & 15;                                                 \
            int phys = (c4 >> 1) ^ (row & 7);                                  \
            *(s16x4*)&lA[buf][row * BK + (h) * 64 + phys * 8 + (c4 & 1) * 4] = \
                cvt4(ar[i]);                                                   \
        }                                                                      \
    } while (0)

    // B frag (wn*4+ni, kt32): 16 B/lane, lanes contiguous (L2-resident Wpk).
#define BLOAD(kt, dst)                                                         \
    do {                                                                       \
        _Pragma("unroll") for (int ni = 0; ni < 4; ++ni)                       \
            dst[ni] = *(const s16x8*)(Bp +                                     \
                ((size_t)((wn * 4 + ni) * 32 + (kt)) * 64 + lane) * 8);        \
    } while (0)

    // A frags, k-chunk kk (0..3): half h = kk>>1, logical c16 = (kk&1)*4+lhi,
    // phys = logical ^ (r&7). Same swizzle family as R13 (verified).
#define READA(c, kk)                                                           \
    do {                                                                       \
        _Pragma("unroll") for (int mi = 0; mi < 8; ++mi) {                     \
            int r  = mi * 16 + l15;                                            \
            af[mi] = *(const s16x8*)&lA[c][r * BK + ((kk) >> 1) * 64 +         \
                         (((((kk) & 1) * 4 + lhi) ^ (r & 7)) << 3)];           \
        }                                                                      \
    } while (0)

#define MFMA(bf)                                                               \
    do {                                                                       \
        __builtin_amdgcn_s_setprio(1);                                         \
        _Pragma("unroll") for (int mi = 0; mi < 8; ++mi)                       \
            _Pragma("unroll") for (int ni = 0; ni < 4; ++ni)                   \
                acc[mi][ni] = __builtin_amdgcn_mfma_f32_16x16x32_bf16(         \
                    af[mi], bf[ni], acc[mi][ni], 0, 0, 0);                     \
        __builtin_amdgcn_s_setprio(0);                                         \
    } while (0)

#define BAR()   __builtin_amdgcn_s_barrier()
#define LGKM0() asm volatile("s_waitcnt lgkmcnt(0)" ::: "memory")
#define VM(n)   asm volatile("s_waitcnt vmcnt(" #n ")" ::: "memory")

    // ---- Prologue: stage A(0) fully; establish queue [B4(kk0),B4(kk1),A4(1,h0)].
    AISSUE(0, 0); VM(0); AWRITE(0, 0);
    AISSUE(0, 1); VM(0); AWRITE(0, 1);
    BLOAD(0, bfA);        // B(0,kk0)
    BLOAD(1, bfB);        // B(0,kk1)
    AISSUE(1, 0);         // A4(1,h0)
    LGKM0();
    BAR();

#pragma unroll 1
    for (int j = 0; j < NP - 1; ++j) {
        const int c = j & 1;
        VM(8);                            // B(j,kk0) resident
        READA(c, 0); MFMA(bfA);
        BLOAD(j * 4 + 2, bfA);            // B(j,kk2)
        VM(8);                            // B(j,kk1)
        READA(c, 1); MFMA(bfB);
        BLOAD(j * 4 + 3, bfB);            // B(j,kk3)
        VM(8);                            // A4(j+1,h0)
        AWRITE(c ^ 1, 0);
        AISSUE(j + 1, 1);                 // A4(j+1,h1)
        VM(8);                            // B(j,kk2)
        READA(c, 2); MFMA(bfA);
        BLOAD((j + 1) * 4 + 0, bfA);      // B(j+1,kk0)
        VM(8);                            // B(j,kk3)
        READA(c, 3); MFMA(bfB);
        BLOAD((j + 1) * 4 + 1, bfB);      // B(j+1,kk1)
        VM(8);                            // A4(j+1,h1)
        AWRITE(c ^ 1, 1);
        if (j + 2 < NP) AISSUE(j + 2, 0); // A4(j+2,h0)
        LGKM0();                          // own A ds_writes visible
        BAR();                            // one barrier per 128 MFMA
    }
    // ---- Peeled last period (j = NP-1, c = 1). Queue: [B4(kk0), B4(kk1)]. ----
    VM(4);
    READA(1, 0); MFMA(bfA);
    BLOAD((NP - 1) * 4 + 2, bfA);
    VM(4);
    READA(1, 1); MFMA(bfB);
    BLOAD((NP - 1) * 4 + 3, bfB);
    VM(4);
    READA(1, 2); MFMA(bfA);
    VM(0);
    READA(1, 3); MFMA(bfB);

    // Epilogue: D frag (mi,ni): m = lhi*4 + rr, n = l15 (verified layout).
#pragma unroll
    for (int mi = 0; mi < 8; ++mi) {
#pragma unroll
        for (int rr = 0; rr < 4; ++rr) {
            int row   = mi * 16 + lhi * 4 + rr;
            float* cp = Cp + (size_t)row * NO + wn * 64 + l15;
#pragma unroll
            for (int ni = 0; ni < 4; ++ni)
                cp[ni * 16] = acc[mi][ni][rr];
        }
    }
#undef AISSUE
#undef AWRITE
#undef BLOAD
#undef READA
#undef MFMA
#undef BAR
#undef LGKM0
#undef VM
}

extern "C" void kernel_launch(void* const* d_in, const int* in_sizes, int n_in,
                              void* d_out, int out_size, void* d_ws, size_t ws_size,
                              hipStream_t stream) {
    const float* X = (const float*)d_in[0];
    const float* W = (const float*)d_in[1];
    float* Out     = (float*)d_out;
    short* Wpk     = (short*)d_ws;   // 8 MiB

    hipLaunchKernelGGL(pack_w, dim3(2048), dim3(256), 0, stream, W, Wpk);
    hipLaunchKernelGGL(moe_gemm, dim3(NE * (NS / BM)), dim3(512), 0,
                       stream, X, Wpk, Out);
}

// Round 17
// 113.993 us; speedup vs baseline: 1.2066x; 1.0124x over previous
//
#include <hip/hip_runtime.h>
#include <hip/hip_bf16.h>

// Grouped GEMM: out[e,s,o] = sum_i x[e,s,i] * w[e,o,i]
// E=8, S=8192 tok/expert, O=512, I=1024, fp32 in/out, bf16 MFMA compute.
// R17 == R13 (best measured: 114.1 us), restored after R14/R15/R16 probes
//      regressed or tied. Consume-first BK=64 periods on BM=128 x BN=512,
//      8 waves, reg-B from fragment-packed Wpk (expert-per-XCD L2-resident),
//      A reg-staged fp32->bf16 into XOR-swizzled LDS, counted vmcnt
//      (never 0 mid-loop), one BAR per BK=64.
//      Plateau note: acc(128)+arch(~124) = 252 regs/wave -> 2 waves/SIMD,
//      single barrier-synced block/CU; MFMA+fabric+LDS+sync pools mostly
//      serialize. 9 structural variants (R8-R16) land 114-138 us; this is
//      the empirical best configuration.

#define NE 8
#define NO 512
#define NI 1024
#define NS 8192

#define BM 128
#define BK 64
#define NP (NI / BK)   // 16 periods (32 BK32 B-tiles)

typedef __attribute__((ext_vector_type(4))) float f32x4;
typedef __attribute__((ext_vector_type(4))) short s16x4;
typedef __attribute__((ext_vector_type(8))) short s16x8;

__device__ __forceinline__ s16x4 cvt4(f32x4 a) {
    s16x4 r;
    r[0] = (short)__builtin_bit_cast(unsigned short, __float2bfloat16(a[0]));
    r[1] = (short)__builtin_bit_cast(unsigned short, __float2bfloat16(a[1]));
    r[2] = (short)__builtin_bit_cast(unsigned short, __float2bfloat16(a[2]));
    r[3] = (short)__builtin_bit_cast(unsigned short, __float2bfloat16(a[3]));
    return r;
}

// ---- pass 0: W fp32 -> bf16, MFMA B-fragment lane order (R3-verified) ----
// Wpk(e, g, kt32, l, j) = bf16(W[e][g*16 + (l&15)][kt32*32 + (l>>4)*8 + j])
__global__ __launch_bounds__(256)
void pack_w(const float* __restrict__ W, short* __restrict__ Wpk) {
    int idx  = blockIdx.x * 256 + threadIdx.x;  // 0 .. 524287
    int l    = idx & 63;
    int kt32 = (idx >> 6) & 31;
    int g    = (idx >> 11) & 31;
    int e    = idx >> 16;
    const float* src = W + (size_t)(e * NO + g * 16 + (l & 15)) * NI
                         + kt32 * 32 + (l >> 4) * 8;
    f32x4 a = *(const f32x4*)src;
    f32x4 b = *(const f32x4*)(src + 4);
    s16x4 lo = cvt4(a), hi = cvt4(b);
    s16x8 r;
    r[0] = lo[0]; r[1] = lo[1]; r[2] = lo[2]; r[3] = lo[3];
    r[4] = hi[0]; r[5] = hi[1]; r[6] = hi[2]; r[7] = hi[3];
    *(s16x8*)(Wpk + (size_t)idx * 8) = r;
}

// ---- main grouped GEMM ----
__global__ __launch_bounds__(512, 1)
void moe_gemm(const float* __restrict__ X,
              const short* __restrict__ Wpk,
              float* __restrict__ Out) {
    // 512 blocks = 8 experts x 64 mblk. e = bid&7 -> one expert per XCD.
    int bid  = blockIdx.x;
    int e    = bid & 7;
    int mblk = bid >> 3;

    const float* Ap = X   + ((size_t)e * NS + (size_t)mblk * BM) * NI;
    const short* Bp = Wpk + (size_t)e * (32 * 32 * 64 * 8);
    float*       Cp = Out + ((size_t)e * NS + (size_t)mblk * BM) * NO;

    __shared__ short lA[2][BM * BK];   // 2 x 16 KiB

    const int tid  = threadIdx.x;
    const int lane = tid & 63;
    const int wn   = tid >> 6;    // 0..7 -> cols [wn*64, +64)
    const int l15  = lane & 15;
    const int lhi  = lane >> 4;   // 0..3

    f32x4 acc[8][4];
#pragma unroll
    for (int i = 0; i < 8; ++i)
#pragma unroll
        for (int j = 0; j < 4; ++j)
            acc[i][j] = (f32x4){0.f, 0.f, 0.f, 0.f};

    f32x4 ar[4];                 // A staging: 4 x f32x4 / thread (128x64 fp32)
    s16x8 bfA[4], bfB[4], af[8]; // named B double-buffer (rule #20)

    // A: unit u = tid + i*512 over 2048 f32x4-chunks of the 128x64 tile.
    // row = u>>4 (0..127), c4 = u&15. 16 lanes x 16B = 256 B/row, coalesced.
#define AISSUE(p)                                                              \
    do {                                                                       \
        _Pragma("unroll") for (int i = 0; i < 4; ++i) {                        \
            int u = tid + i * 512;                                             \
            ar[i] = *(const f32x4*)(Ap + (size_t)(u >> 4) * NI +               \
                                    (p) * BK + (u & 15) * 4);                  \
        }                                                                      \
    } while (0)

    // A write: 16B-chunk c16 = c4>>1, phys = c16 ^ (row&7). (R8-verified)
#define AWRITE(buf)                                                            \
    do {                                                                       \
        _Pragma("unroll") for (int i = 0; i < 4; ++i) {                        \
            int u    = tid + i * 512;                                          \
            int row  = u >> 4;                                                 \
            int c4   = u & 15;                                                 \
            int phys = (c4 >> 1) ^ (row & 7);                                  \
            *(s16x4*)&lA[buf][row * BK + phys * 8 + (c4 & 1) * 4] = cvt4(ar[i]); \
        }                                                                      \
    } while (0)

    // B frag (wn*4+ni, kt32): 16 B/lane, lanes contiguous (L2). kt32 = 0..31.
#define BLOAD(kt, dst)                                                         \
    do {                                                                       \
        _Pragma("unroll") for (int ni = 0; ni < 4; ++ni)                       \
            dst[ni] = *(const s16x8*)(Bp +                                     \
                ((size_t)((wn * 4 + ni) * 32 + (kt)) * 64 + lane) * 8);        \
    } while (0)

    // A frags, k-half kk: row r = mi*16+l15, phys = (kk*4+lhi) ^ (r&7). (R9-verified)
#define READA(c, kk)                                                           \
    do {                                                                       \
        _Pragma("unroll") for (int mi = 0; mi < 8; ++mi) {                     \
            int r  = mi * 16 + l15;                                            \
            af[mi] = *(const s16x8*)&lA[c][r * BK +                            \
                                           ((((kk) * 4 + lhi) ^ (r & 7)) << 3)]; \
        }                                                                      \
    } while (0)

#define MFMA(bf)                                                               \
    do {                                                                       \
        __builtin_amdgcn_s_setprio(1);                                         \
        _Pragma("unroll") for (int mi = 0; mi < 8; ++mi)                       \
            _Pragma("unroll") for (int ni = 0; ni < 4; ++ni)                   \
                acc[mi][ni] = __builtin_amdgcn_mfma_f32_16x16x32_bf16(         \
                    af[mi], bf[ni], acc[mi][ni], 0, 0, 0);                     \
        __builtin_amdgcn_s_setprio(0);                                         \
    } while (0)

#define BAR()   __builtin_amdgcn_s_barrier()
#define LGKM0() asm volatile("s_waitcnt lgkmcnt(0)" ::: "memory")
#define VM(n)   asm volatile("s_waitcnt vmcnt(" #n ")" ::: "memory")

    // ---- Prologue. Invariant entering period j:
    //      lA[j&1] = A(j); bfA,bfB = B(2j),B(2j+1) pending in queue;
    //      vm queue = [B8(j) oldest, A4(j+1)] = 12. ----
    AISSUE(0);
    VM(0);
    AWRITE(0);
    BLOAD(0, bfA);     // B8(0)...
    BLOAD(1, bfB);
    AISSUE(1);         // A4(1)
    LGKM0();
    BAR();

#pragma unroll 1
    for (int j = 0; j < NP - 1; ++j) {
        const int c = j & 1;
        // consume-first: everything below VM(4) is resident.
        VM(4);                       // drain B8(j); keep A4(j+1)
        READA(c, 0);
        MFMA(bfA);
        BLOAD(2 * j + 2, bfA);       // B for period j+1, first half
        READA(c, 1);
        MFMA(bfB);
        BLOAD(2 * j + 3, bfB);       // B for period j+1, second half
        // stage-behind:
        VM(8);                       // drain A4(j+1); keep B8(j+1)
        AWRITE(c ^ 1);
        if (j < NP - 2) AISSUE(j + 2);
        LGKM0();                     // own ds_writes visible
        BAR();
    }
    // ---- Period 15: consume only. Queue entering: [B8(15)] = 8. ----
    VM(4);
    READA(1, 0);
    MFMA(bfA);
    VM(0);
    READA(1, 1);
    MFMA(bfB);

    // Epilogue: D frag (mi,ni): m = lhi*4 + rr, n = l15 (verified layout).
#pragma unroll
    for (int mi = 0; mi < 8; ++mi) {
#pragma unroll
        for (int rr = 0; rr < 4; ++rr) {
            int row   = mi * 16 + lhi * 4 + rr;
            float* cp = Cp + (size_t)row * NO + wn * 64 + l15;
#pragma unroll
            for (int ni = 0; ni < 4; ++ni)
                cp[ni * 16] = acc[mi][ni][rr];
        }
    }
#undef AISSUE
#undef AWRITE
#undef BLOAD
#undef READA
#undef MFMA
#undef BAR
#undef LGKM0
#undef VM
}

extern "C" void kernel_launch(void* const* d_in, const int* in_sizes, int n_in,
                              void* d_out, int out_size, void* d_ws, size_t ws_size,
                              hipStream_t stream) {
    const float* X = (const float*)d_in[0];
    const float* W = (const float*)d_in[1];
    float* Out     = (float*)d_out;
    short* Wpk     = (short*)d_ws;   // 8 MiB

    hipLaunchKernelGGL(pack_w, dim3(2048), dim3(256), 0, stream, W, Wpk);
    hipLaunchKernelGGL(moe_gemm, dim3(NE * (NS / BM)), dim3(512), 0,
                       stream, X, Wpk, Out);
}